// Round 1
// baseline (1996.642 us; speedup 1.0000x reference)
//
#include <hip/hip_runtime.h>
#include <math.h>

// Problem dims (fixed by the reference setup_inputs):
static constexpr int B = 4, C = 64, H = 160, W = 160;
static constexpr int HW = H * W;          // 25600
static constexpr int CHW = C * HW;        // 1638400
static constexpr int NELEM = B * CHW;     // 6553600

__device__ __forceinline__ float lrelu(float v) { return v >= 0.f ? v : 0.1f * v; }

// ---------------------------------------------------------------------------
// Kernel A: 1x1 conv over concat(aux, ref) [128 ch] -> 64 ch, + bias + lrelu
// one thread per output element
// ---------------------------------------------------------------------------
__global__ __launch_bounds__(256) void k_conv1x1_in(
    const float* __restrict__ aux, const float* __restrict__ ref,
    const float* __restrict__ w, const float* __restrict__ bias,
    float* __restrict__ out) {
  int idx = blockIdx.x * 256 + threadIdx.x;
  int b = idx / CHW;
  int rem = idx - b * CHW;
  int co = rem / HW;
  int hw = rem - co * HW;
  const float* wa = w + co * 128;
  const float* pa = aux + b * CHW + hw;
  const float* pr = ref + b * CHW + hw;
  float acc = bias[co];
#pragma unroll 8
  for (int ci = 0; ci < 64; ++ci) acc += pa[ci * HW] * wa[ci];
#pragma unroll 8
  for (int ci = 0; ci < 64; ++ci) acc += pr[ci * HW] * wa[64 + ci];
  out[idx] = lrelu(acc);
}

// ---------------------------------------------------------------------------
// Kernel B: dilated 3x3 conv 64->64, + bias + lrelu. LDS-tiled 16x16 spatial,
// each block computes 16 output channels (co-split 4 for occupancy).
// grid: (10, 10, B*4)
// ---------------------------------------------------------------------------
template <int D>
__global__ __launch_bounds__(256) void k_conv3x3(
    const float* __restrict__ in, const float* __restrict__ w,
    const float* __restrict__ bias, float* __restrict__ out) {
  constexpr int TS = 16 + 2 * D;
  __shared__ float tile[TS * TS];
  int b = blockIdx.z >> 2;
  int cog = (blockIdx.z & 3) * 16;
  int gx0 = blockIdx.x * 16, gy0 = blockIdx.y * 16;
  int tid = threadIdx.x;
  int tx = tid & 15, ty = tid >> 4;
  float acc[16];
#pragma unroll
  for (int j = 0; j < 16; ++j) acc[j] = 0.f;
  const float* src = in + b * CHW;
  for (int ci = 0; ci < 64; ++ci) {
    const float* sc = src + ci * HW;
    for (int i = tid; i < TS * TS; i += 256) {
      int ly = i / TS, lx = i - ly * TS;
      int gy = gy0 + ly - D, gx = gx0 + lx - D;
      float v = 0.f;
      if (gy >= 0 && gy < H && gx >= 0 && gx < W) v = sc[gy * W + gx];
      tile[i] = v;
    }
    __syncthreads();
    float s[9];
#pragma unroll
    for (int ky = 0; ky < 3; ++ky)
#pragma unroll
      for (int kx = 0; kx < 3; ++kx)
        s[ky * 3 + kx] = tile[(ty + ky * D) * TS + tx + kx * D];
#pragma unroll
    for (int j = 0; j < 16; ++j) {
      const float* wj = w + ((cog + j) * 64 + ci) * 9;  // uniform -> scalar loads
      float a = acc[j];
#pragma unroll
      for (int k = 0; k < 9; ++k) a += s[k] * wj[k];
      acc[j] = a;
    }
    __syncthreads();
  }
  int obase = (b * 64 + cog) * HW + (gy0 + ty) * W + gx0 + tx;
#pragma unroll
  for (int j = 0; j < 16; ++j)
    out[obase + j * HW] = lrelu(acc[j] + bias[cog + j]);
}

// ---------------------------------------------------------------------------
// Kernel C: 1x1 conv over concat(r1,r2,r3) [192 ch] -> 64, + bias, + residual
// (in-place into off_x). No activation.
// ---------------------------------------------------------------------------
__global__ __launch_bounds__(256) void k_aspp_merge(
    const float* __restrict__ r1, const float* __restrict__ r2,
    const float* __restrict__ r3, const float* __restrict__ w,
    const float* __restrict__ bias, float* __restrict__ off0) {
  int idx = blockIdx.x * 256 + threadIdx.x;
  int b = idx / CHW;
  int rem = idx - b * CHW;
  int co = rem / HW;
  int hw = rem - co * HW;
  const float* wp = w + co * 192;
  const float* p1 = r1 + b * CHW + hw;
  const float* p2 = r2 + b * CHW + hw;
  const float* p3 = r3 + b * CHW + hw;
  float acc = bias[co];
#pragma unroll 8
  for (int ci = 0; ci < 64; ++ci) acc += p1[ci * HW] * wp[ci];
#pragma unroll 8
  for (int ci = 0; ci < 64; ++ci) acc += p2[ci * HW] * wp[64 + ci];
#pragma unroll 8
  for (int ci = 0; ci < 64; ++ci) acc += p3[ci * HW] * wp[128 + ci];
  off0[idx] += acc;
}

// ---------------------------------------------------------------------------
// Kernel D: 1x1 conv 64 -> 18 (offset head), + bias, no activation.
// ---------------------------------------------------------------------------
__global__ __launch_bounds__(256) void k_conv_off(
    const float* __restrict__ in, const float* __restrict__ w,
    const float* __restrict__ bias, float* __restrict__ out) {
  int idx = blockIdx.x * 256 + threadIdx.x;  // B*18*HW total
  int b = idx / (18 * HW);
  int rem = idx - b * (18 * HW);
  int ko = rem / HW;
  int hw = rem - ko * HW;
  const float* wp = w + ko * 64;
  const float* p = in + b * CHW + hw;
  float acc = bias[ko];
#pragma unroll 8
  for (int ci = 0; ci < 64; ++ci) acc += p[ci * HW] * wp[ci];
  out[idx] = acc;
}

// ---------------------------------------------------------------------------
// Kernel E: deformable 3x3 conv (torchvision offset layout: ch 2k=dy, 2k+1=dx,
// tap k = ky*3+kx). One thread per spatial position, 32 out-channel accs,
// o-split 2 via blockIdx.y. grid: (B*HW/256, 2)
// ---------------------------------------------------------------------------
__global__ __launch_bounds__(256) void k_deform(
    const float* __restrict__ x, const float* __restrict__ offs,
    const float* __restrict__ w, const float* __restrict__ bias,
    float* __restrict__ out) {
  int pos = blockIdx.x * 256 + threadIdx.x;  // 0 .. B*HW-1
  int og = blockIdx.y * 32;
  int b = pos / HW;
  int hw = pos - b * HW;
  int h = hw / W;
  int wv = hw - h * W;
  const float* xb = x + b * CHW;
  const float* ob = offs + b * 18 * HW + hw;
  float acc[32];
#pragma unroll
  for (int j = 0; j < 32; ++j) acc[j] = 0.f;

  for (int k = 0; k < 9; ++k) {
    int ky = k / 3, kx = k - ky * 3;
    float dy = ob[(2 * k) * HW];
    float dx = ob[(2 * k + 1) * HW];
    float py = dy + (float)(h - 1 + ky);
    float px = dx + (float)(wv - 1 + kx);
    float fy = floorf(py), fx = floorf(px);
    int iy0 = (int)fy, ix0 = (int)fx;
    float wy = py - fy, wx = px - fx;
    int iy1 = iy0 + 1, ix1 = ix0 + 1;
    float vy0 = (iy0 >= 0 && iy0 < H) ? 1.f : 0.f;
    float vy1 = (iy1 >= 0 && iy1 < H) ? 1.f : 0.f;
    float vx0 = (ix0 >= 0 && ix0 < W) ? 1.f : 0.f;
    float vx1 = (ix1 >= 0 && ix1 < W) ? 1.f : 0.f;
    int cy0 = min(max(iy0, 0), H - 1), cy1 = min(max(iy1, 0), H - 1);
    int cx0 = min(max(ix0, 0), W - 1), cx1 = min(max(ix1, 0), W - 1);
    float c00 = vy0 * vx0 * (1.f - wy) * (1.f - wx);
    float c01 = vy0 * vx1 * (1.f - wy) * wx;
    float c10 = vy1 * vx0 * wy * (1.f - wx);
    float c11 = vy1 * vx1 * wy * wx;
    int a00 = cy0 * W + cx0, a01 = cy0 * W + cx1;
    int a10 = cy1 * W + cx0, a11 = cy1 * W + cx1;
#pragma unroll 4
    for (int ci = 0; ci < 64; ++ci) {
      const float* xc = xb + ci * HW;
      float s = c00 * xc[a00] + c01 * xc[a01] + c10 * xc[a10] + c11 * xc[a11];
      const float* wp = w + ci * 9 + k;  // w[o][ci][k], o stride 576; uniform
#pragma unroll
      for (int j = 0; j < 32; ++j) acc[j] += s * wp[(og + j) * 576];
    }
  }
  int obase = (b * 64 + og) * HW + hw;
#pragma unroll
  for (int j = 0; j < 32; ++j)
    out[obase + j * HW] = acc[j] + bias[og + j];
}

// ---------------------------------------------------------------------------
extern "C" void kernel_launch(void* const* d_in, const int* in_sizes, int n_in,
                              void* d_out, int out_size, void* d_ws, size_t ws_size,
                              hipStream_t stream) {
  const float* aux = (const float*)d_in[0];
  const float* ref = (const float*)d_in[1];
  const float* w01 = (const float*)d_in[2];
  const float* b01 = (const float*)d_in[3];
  const float* a1w = (const float*)d_in[4];
  const float* a1b = (const float*)d_in[5];
  const float* a2w = (const float*)d_in[6];
  const float* a2b = (const float*)d_in[7];
  const float* a3w = (const float*)d_in[8];
  const float* a3b = (const float*)d_in[9];
  const float* arw = (const float*)d_in[10];
  const float* arb = (const float*)d_in[11];
  const float* w02 = (const float*)d_in[12];
  const float* b02 = (const float*)d_in[13];
  const float* dw  = (const float*)d_in[14];
  const float* db  = (const float*)d_in[15];
  float* out = (float*)d_out;

  float* off0 = (float*)d_ws;          // [B,64,H,W] off_x (and final off_x after merge)
  float* r1 = off0 + NELEM;            // [B,64,H,W]
  float* r2 = r1 + NELEM;
  float* r3 = r2 + NELEM;
  float* offs = r3 + NELEM;            // [B,18,H,W]

  k_conv1x1_in<<<NELEM / 256, 256, 0, stream>>>(aux, ref, w01, b01, off0);

  dim3 g3(W / 16, H / 16, B * 4);
  k_conv3x3<1><<<g3, 256, 0, stream>>>(off0, a1w, a1b, r1);
  k_conv3x3<2><<<g3, 256, 0, stream>>>(off0, a2w, a2b, r2);
  k_conv3x3<4><<<g3, 256, 0, stream>>>(off0, a3w, a3b, r3);

  k_aspp_merge<<<NELEM / 256, 256, 0, stream>>>(r1, r2, r3, arw, arb, off0);
  k_conv_off<<<(B * 18 * HW) / 256, 256, 0, stream>>>(off0, w02, b02, offs);

  dim3 gd(B * HW / 256, 2);
  k_deform<<<gd, 256, 0, stream>>>(aux, offs, dw, db, out);
}